// Round 9
// baseline (368.945 us; speedup 1.0000x reference)
//
#include <hip/hip_runtime.h>

typedef short s16x8 __attribute__((ext_vector_type(8)));
typedef float f32x4 __attribute__((ext_vector_type(4)));

#define MFMA16(a, b, c) __builtin_amdgcn_mfma_f32_16x16x32_bf16((a), (b), (c), 0, 0, 0)

// ---------- bf16 helpers (RNE) ----------
__device__ __forceinline__ float b2f(unsigned short u) {
    union { unsigned int i; float f; } c;
    c.i = ((unsigned int)u) << 16;
    return c.f;
}
__device__ __forceinline__ unsigned short f2b(float f) {
    union { float f; unsigned int i; } c;
    c.f = f;
    unsigned int i = c.i + 0x7FFFu + ((c.i >> 16) & 1u);
    return (unsigned short)(i >> 16);
}

// async global->LDS, 16B per lane; LDS dest = wave-uniform base + lane*16 [m97/m104]
__device__ __forceinline__ void gl_lds16(const unsigned short* g, unsigned short* l) {
    __builtin_amdgcn_global_load_lds(
        (const __attribute__((address_space(1))) void*)g,
        (__attribute__((address_space(3))) void*)l, 16, 0, 0);
}

// cheap exact-enough GELU: 0.5v(1+tanh(0.79788456(v+0.044715v^3))) via one exp
__device__ __forceinline__ float gelu_f(float v) {
    float u2 = 1.5957691216057308f * v * (1.0f + 0.044715f * v * v);  // 2u
    float t = __expf(fminf(u2, 80.0f));
    return v * t * __builtin_amdgcn_rcpf(t + 1.0f);
}

// ---------- problem constants ----------
// B=2, T=2048, D=1024, H=16, HD=64, M = B*T = 4096. f32 I/O, bf16 internals.
static constexpr size_t OFF_WAT = 0;                         // w_attn^T [3072][1024] bf16
static constexpr size_t OFF_WPT = OFF_WAT + 6291456;         // w_proj^T [1024][1024]
static constexpr size_t OFF_WFT = OFF_WPT + 2097152;         // w_fc^T   [4096][1024]
static constexpr size_t OFF_WOT = OFF_WFT + 8388608;         // w_out^T  [1024][4096]
static constexpr size_t OFF_R1  = OFF_WOT + 8388608;         // xn1 / h2 [4096][1024] bf16
static constexpr size_t OFF_R2  = OFF_R1 + 8388608;          // qkv [4096][3072]; later g [4096][4096]
static constexpr size_t OFF_VT  = OFF_R2 + 25165824;         // vt [32][64][2048] bf16
static constexpr size_t OFF_Y   = OFF_VT + 8388608;          // y [4096][1024] bf16
static constexpr size_t OFF_X2  = OFF_Y + 8388608;           // x2 [4096][1024] f32

// ---------- fused: 4 weight transposes (f32->bf16) + LN1 ----------
__global__ __launch_bounds__(256) void prep_kernel(const float* __restrict__ wA,
                                                   const float* __restrict__ wP,
                                                   const float* __restrict__ wF,
                                                   const float* __restrict__ wO,
                                                   unsigned short* __restrict__ WaT,
                                                   unsigned short* __restrict__ WpT,
                                                   unsigned short* __restrict__ WfT,
                                                   unsigned short* __restrict__ WoT,
                                                   const float* __restrict__ x,
                                                   const float* __restrict__ g1,
                                                   const float* __restrict__ b1,
                                                   unsigned short* __restrict__ xn1) {
    __shared__ unsigned short tile[32][33];
    __shared__ float red[2][4];
    const int bb = blockIdx.x;
    if (bb >= 12288) {
        const int row = bb - 12288;
        const int t = threadIdx.x;
        float4 f = ((const float4*)(x + (size_t)row * 1024))[t];
        float v[4] = {f.x, f.y, f.z, f.w};
        float s = v[0] + v[1] + v[2] + v[3];
        float ss = v[0] * v[0] + v[1] * v[1] + v[2] * v[2] + v[3] * v[3];
#pragma unroll
        for (int o = 32; o >= 1; o >>= 1) {
            s += __shfl_down(s, o);
            ss += __shfl_down(ss, o);
        }
        const int wv = t >> 6, ln = t & 63;
        if (ln == 0) { red[0][wv] = s; red[1][wv] = ss; }
        __syncthreads();
        s = red[0][0] + red[0][1] + red[0][2] + red[0][3];
        ss = red[1][0] + red[1][1] + red[1][2] + red[1][3];
        const float mu = s * (1.0f / 1024.0f);
        const float rs = rsqrtf(ss * (1.0f / 1024.0f) - mu * mu + 1e-5f);
        float4 gg = ((const float4*)g1)[t];
        float4 bbv = ((const float4*)b1)[t];
        ushort4 o4;
        o4.x = f2b((v[0] - mu) * rs * gg.x + bbv.x);
        o4.y = f2b((v[1] - mu) * rs * gg.y + bbv.y);
        o4.z = f2b((v[2] - mu) * rs * gg.z + bbv.z);
        o4.w = f2b((v[3] - mu) * rs * gg.w + bbv.w);
        ((ushort4*)(xn1 + (size_t)row * 1024))[t] = o4;
        return;
    }
    const float* W;
    unsigned short* Wt;
    int K, N, rel;
    if (bb < 3072)      { W = wA; Wt = WaT; K = 1024; N = 3072; rel = bb; }
    else if (bb < 4096) { W = wP; Wt = WpT; K = 1024; N = 1024; rel = bb - 3072; }
    else if (bb < 8192) { W = wF; Wt = WfT; K = 1024; N = 4096; rel = bb - 4096; }
    else                { W = wO; Wt = WoT; K = 4096; N = 1024; rel = bb - 8192; }
    const int ntx = N >> 5;
    const int n0 = (rel % ntx) * 32, k0 = (rel / ntx) * 32;
    const int tx = threadIdx.x & 31, ty = threadIdx.x >> 5;  // 32 x 8
#pragma unroll
    for (int i = 0; i < 32; i += 8)
        tile[ty + i][tx] = f2b(W[(size_t)(k0 + ty + i) * N + (n0 + tx)]);
    __syncthreads();
#pragma unroll
    for (int i = 0; i < 32; i += 8)
        Wt[(size_t)(n0 + ty + i) * K + (k0 + tx)] = tile[tx][ty + i];
}

// ---------- layernorm (LN2): f32 in, bf16 out; also copies x2 -> outf (resid base) ----------
__global__ __launch_bounds__(256) void ln_kernel(const float* __restrict__ xin,
                                                 const float* __restrict__ gw,
                                                 const float* __restrict__ bw,
                                                 unsigned short* __restrict__ out,
                                                 float* __restrict__ copyf) {
    const int row = blockIdx.x;
    const int t = threadIdx.x;
    float4 f = ((const float4*)(xin + (size_t)row * 1024))[t];
    if (copyf) ((float4*)(copyf + (size_t)row * 1024))[t] = f;
    float v[4] = {f.x, f.y, f.z, f.w};
    float s = v[0] + v[1] + v[2] + v[3];
    float ss = v[0] * v[0] + v[1] * v[1] + v[2] * v[2] + v[3] * v[3];
#pragma unroll
    for (int o = 32; o >= 1; o >>= 1) {
        s += __shfl_down(s, o);
        ss += __shfl_down(ss, o);
    }
    __shared__ float red[2][4];
    const int wv = t >> 6, ln = t & 63;
    if (ln == 0) { red[0][wv] = s; red[1][wv] = ss; }
    __syncthreads();
    s = red[0][0] + red[0][1] + red[0][2] + red[0][3];
    ss = red[1][0] + red[1][1] + red[1][2] + red[1][3];
    const float mu = s * (1.0f / 1024.0f);
    const float rs = rsqrtf(ss * (1.0f / 1024.0f) - mu * mu + 1e-5f);
    float4 gg = ((const float4*)gw)[t];
    float4 bb = ((const float4*)bw)[t];
    ushort4 o4;
    o4.x = f2b((v[0] - mu) * rs * gg.x + bb.x);
    o4.y = f2b((v[1] - mu) * rs * gg.y + bb.y);
    o4.z = f2b((v[2] - mu) * rs * gg.z + bb.z);
    o4.w = f2b((v[3] - mu) * rs * gg.w + bb.w);
    ((ushort4*)(out + (size_t)row * 1024))[t] = o4;
}

// ---------- GEMM: C[M][N] = A[M][K] @ Bt[N][K]^T ----------
// 128xBN tile, BK=64, global_load_lds staging, XOR-swizzled LDS (chunk ^= row&7).
// EPI: 0 = bf16 store; 1 = gelu -> bf16; 2 = f32 out = f32 resid + acc;
//      3 = qkv (V transposed to vt); 4 = split-K atomic f32 add into outp
template <int EPI, int BN>
__global__ __launch_bounds__(256) void gemm_bt(const unsigned short* __restrict__ A,
                                               const unsigned short* __restrict__ Bt,
                                               void* __restrict__ outp,
                                               const float* __restrict__ residp,
                                               unsigned short* __restrict__ vtp,
                                               int M, int N, int K) {
    constexpr int NWC = (BN == 128) ? 2 : 1;  // wave cols
    constexpr int AI  = (BN == 128) ? 4 : 2;  // 16-row groups per wave
    constexpr int PB  = BN / 32;              // B staging instrs per wave
    __shared__ unsigned short As[128 * 64];
    __shared__ unsigned short Bs[BN * 64];
    const int m0 = blockIdx.y * 128, n0 = blockIdx.x * BN;
    const int tid = threadIdx.x;
    const int w = tid >> 6, lane = tid & 63, quad = lane >> 4, lk = lane & 15;
    const int wr = w / NWC, wc = w % NWC;
    const int lrow = lane >> 3, lchunk = lane & 7;
    const int cg = lchunk ^ (lrow & 7);  // global 16B-chunk this lane fetches

    const unsigned short* aP = A + (size_t)(m0 + w * 32 + lrow) * K + cg * 8;
    const unsigned short* bP = Bt + (size_t)(n0 + w * (BN / 4) + lrow) * K + cg * 8;
    unsigned short* lA = As + (w * 32) * 64;
    unsigned short* lB = Bs + (w * (BN / 4)) * 64;

    f32x4 acc[AI][4];
#pragma unroll
    for (int i = 0; i < AI; ++i)
#pragma unroll
        for (int j = 0; j < 4; ++j) acc[i][j] = (f32x4){0.f, 0.f, 0.f, 0.f};

    // split-K (EPI 4): blockIdx.z selects a 16-iteration K-range
    const int kb0 = (EPI == 4) ? blockIdx.z * 16 : 0;
    const int kb1 = (EPI == 4) ? kb0 + 16 : (K >> 6);
    for (int kb = kb0; kb < kb1; ++kb) {
        const unsigned short* aPk = aP + kb * 64;
        const unsigned short* bPk = bP + kb * 64;
#pragma unroll
        for (int p = 0; p < 4; ++p)
            gl_lds16(aPk + (size_t)p * 8 * K, lA + p * 8 * 64);
#pragma unroll
        for (int p = 0; p < PB; ++p)
            gl_lds16(bPk + (size_t)p * 8 * K, lB + p * 8 * 64);
        __syncthreads();  // drains vmcnt -> LDS tiles visible
#pragma unroll
        for (int ks = 0; ks < 2; ++ks) {
            const int s = (ks * 4 + quad) ^ (lk & 7);
            s16x8 af[AI], bfv[4];
#pragma unroll
            for (int i = 0; i < AI; ++i)
                af[i] = *(const s16x8*)(As + (wr * (AI * 16) + i * 16 + lk) * 64 + s * 8);
#pragma unroll
            for (int j = 0; j < 4; ++j)
                bfv[j] = *(const s16x8*)(Bs + (wc * 64 + j * 16 + lk) * 64 + s * 8);
#pragma unroll
            for (int i = 0; i < AI; ++i)
#pragma unroll
                for (int j = 0; j < 4; ++j)
                    acc[i][j] = MFMA16(af[i], bfv[j], acc[i][j]);
        }
        __syncthreads();  // protect LDS before next overwrite
    }

    // epilogue: C/D layout col = lane&15, row = quad*4 + reg  [m89-verified]
    const int gr0 = m0 + wr * (AI * 16);
    const int gc0 = n0 + wc * 64;
    if constexpr (EPI == 2) {
#pragma unroll
        for (int i = 0; i < AI; ++i)
#pragma unroll
            for (int r = 0; r < 4; ++r) {
                const int gr = gr0 + i * 16 + quad * 4 + r;
                const size_t ro = (size_t)gr * N;
#pragma unroll
                for (int j = 0; j < 4; ++j) {
                    const int gc = gc0 + j * 16 + lk;
                    ((float*)outp)[ro + gc] = residp[ro + gc] + acc[i][j][r];
                }
            }
    } else if constexpr (EPI == 4) {
        // split-K: atomic f32 accumulate into pre-initialized output
#pragma unroll
        for (int i = 0; i < AI; ++i)
#pragma unroll
            for (int r = 0; r < 4; ++r) {
                const int gr = gr0 + i * 16 + quad * 4 + r;
                const size_t ro = (size_t)gr * N;
#pragma unroll
                for (int j = 0; j < 4; ++j) {
                    const int gc = gc0 + j * 16 + lk;
                    unsafeAtomicAdd(&((float*)outp)[ro + gc], acc[i][j][r]);
                }
            }
    } else if (EPI == 3 && gc0 >= 2048) {
        // V block: store transposed into vt[(bh*64+d)*2048 + t]
        const int h = (gc0 - 2048) >> 6;
        const int bq = m0 >> 11;
        const size_t vb = (size_t)(bq * 16 + h) * 64;
        const int tg0 = (m0 & 2047) + wr * (AI * 16);
        unsigned short* Ept = As + w * 2048;  // [64 d][24] shorts (16B-aligned rows)
#pragma unroll
        for (int i = 0; i < AI; ++i) {
#pragma unroll
            for (int j = 0; j < 4; ++j)
#pragma unroll
                for (int r = 0; r < 4; ++r)
                    Ept[(j * 16 + lk) * 24 + quad * 4 + r] = f2b(acc[i][j][r]);
            const int d = lane;
#pragma unroll
            for (int half = 0; half < 2; ++half) {
                uint4 dd = *(const uint4*)(Ept + d * 24 + half * 8);
                *(uint4*)(vtp + (vb + d) * 2048 + tg0 + i * 16 + half * 8) = dd;
            }
        }
    } else {
        // bf16: stage through LDS, reload 16B/lane, full-line dwordx4 stores
        unsigned short* Ep = As + w * (16 * 72);  // per-wave [16][72] bf16
#pragma unroll
        for (int i = 0; i < AI; ++i) {
#pragma unroll
            for (int j = 0; j < 4; ++j)
#pragma unroll
                for (int r = 0; r < 4; ++r) {
                    float v = acc[i][j][r];
                    if constexpr (EPI == 1) v = gelu_f(v);
                    Ep[(quad * 4 + r) * 72 + j * 16 + lk] = f2b(v);
                }
#pragma unroll
            for (int c = 0; c < 2; ++c) {
                const int row = c * 8 + lrow;
                uint4 d = *(const uint4*)(Ep + row * 72 + lchunk * 8);
                const int gr = gr0 + i * 16 + row;
                *(uint4*)((unsigned short*)outp + (size_t)gr * N + gc0 + lchunk * 8) = d;
            }
        }
    }
}

// ---------- causal flash attention, GEMM-shaped (R6-verified) ----------
__global__ __launch_bounds__(256) void attn_kernel(const unsigned short* __restrict__ qkv,
                                                   const unsigned short* __restrict__ vt,
                                                   unsigned short* __restrict__ y) {
    __shared__ unsigned short Ks[64 * 64];            // [key][d], swizzled
    __shared__ unsigned short Vs[64 * 64];            // [d][key], swizzled
    __shared__ __align__(16) unsigned short Ps[4][2][576];  // per wave, per subtile [16][36]
    const int tid = threadIdx.x;
    const int w = tid >> 6, lane = tid & 63, quad = lane >> 4, lk = lane & 15;
    const int bb = blockIdx.x;
    const int bh = bb & 31;
    const int p = bb >> 5;               // 0..15
    const int b = bh >> 4, h = bh & 15;
    const size_t rowbase = (size_t)b * 2048;
    const size_t vbase = (size_t)bh * 64;
    const int nt = 32 - p;               // staged k-tiles
    const int rq[2] = {p * 64 + w * 16, (31 - p) * 64 + w * 16};

    const int lrow = lane >> 3, lchunk = lane & 7;

    // Q fragments for both subtiles (A-layout), pre-scaled by 1/8 (exact)
    s16x8 qf[2][2];
#pragma unroll
    for (int si = 0; si < 2; ++si)
#pragma unroll
        for (int ks = 0; ks < 2; ++ks) {
            s16x8 q = *(const s16x8*)(qkv + (rowbase + rq[si] + lk) * 3072 + h * 64 +
                                      ks * 32 + quad * 8);
#pragma unroll
            for (int e = 0; e < 8; ++e) {
                union { unsigned int i; float f; } cc;
                cc.i = ((unsigned int)(unsigned short)q[e]) << 16;
                cc.f *= 0.125f;
                q[e] = (short)(cc.i >> 16);
            }
            qf[si][ks] = q;
        }

    f32x4 oacc[2][4];
    float rsum[2][4];
#pragma unroll
    for (int si = 0; si < 2; ++si) {
#pragma unroll
        for (int dj = 0; dj < 4; ++dj) oacc[si][dj] = (f32x4){0.f, 0.f, 0.f, 0.f};
#pragma unroll
        for (int r = 0; r < 4; ++r) rsum[si][r] = 0.f;
    }

    const int srow = w * 16 + lrow;
    const int cgs = lchunk ^ (srow & 7);
    const unsigned short* kgp = qkv + (rowbase + srow) * 3072 + 1024 + h * 64 + cgs * 8;
    const unsigned short* vgp = vt + (vbase + srow) * 2048 + cgs * 8;
    unsigned short* kl = Ks + w * 1024;
    unsigned short* vl = Vs + w * 1024;

    for (int t = 0; t < nt; ++t) {
#pragma unroll
        for (int i = 0; i < 2; ++i) {
            gl_lds16(kgp + ((size_t)t * 64 + i * 8) * 3072, kl + i * 512);
            gl_lds16(vgp + t * 64 + (size_t)i * 8 * 2048, vl + i * 512);
        }
        __syncthreads();
#pragma unroll
        for (int half = 0; half < 2; ++half) {
            const int k0 = t * 64 + half * 32;
            s16x8 kf[2][2], vf[4];
#pragma unroll
            for (int nj = 0; nj < 2; ++nj)
#pragma unroll
                for (int ks = 0; ks < 2; ++ks) {
                    const int row = half * 32 + nj * 16 + lk;
                    const int s = (ks * 4 + quad) ^ (lk & 7);
                    kf[nj][ks] = *(const s16x8*)(Ks + row * 64 + s * 8);
                }
#pragma unroll
            for (int dj = 0; dj < 4; ++dj) {
                const int s = (half * 4 + quad) ^ (lk & 7);
                vf[dj] = *(const s16x8*)(Vs + (dj * 16 + lk) * 64 + s * 8);
            }
#pragma unroll
            for (int si = 0; si < 2; ++si) {
                const int r0 = rq[si];
                if (k0 > r0 + 15) continue;
                const bool domask = (k0 + 31 > r0);
                f32x4 s[2];
                s[0] = (f32x4){0.f, 0.f, 0.f, 0.f};
                s[1] = (f32x4){0.f, 0.f, 0.f, 0.f};
#pragma unroll
                for (int ks = 0; ks < 2; ++ks) {
                    s[0] = MFMA16(qf[si][ks], kf[0][ks], s[0]);
                    s[1] = MFMA16(qf[si][ks], kf[1][ks], s[1]);
                }
                unsigned short* Pw = Ps[w][si];
#pragma unroll
                for (int nj = 0; nj < 2; ++nj)
#pragma unroll
                    for (int r = 0; r < 4; ++r) {
                        float pv = __expf(s[nj][r]);
                        if (domask) {
                            const int key = k0 + nj * 16 + lk;
                            const int row = r0 + quad * 4 + r;
                            if (key > row) pv = 0.f;
                        }
                        union { float f; unsigned int i; } cc;
                        cc.f = pv;
                        cc.i &= 0xFFFF0000u;
                        rsum[si][r] += cc.f;
                        Pw[(quad * 4 + r) * 36 + nj * 16 + lk] = (unsigned short)(cc.i >> 16);
                    }
                const s16x8 af = *(const s16x8*)(Pw + lk * 36 + quad * 8);
#pragma unroll
                for (int dj = 0; dj < 4; ++dj)
                    oacc[si][dj] = MFMA16(af, vf[dj], oacc[si][dj]);
            }
        }
        __syncthreads();
    }

#pragma unroll
    for (int si = 0; si < 2; ++si) {
#pragma unroll
        for (int o = 1; o < 16; o <<= 1)
#pragma unroll
            for (int r = 0; r < 4; ++r) rsum[si][r] += __shfl_xor(rsum[si][r], o);
        float inv[4];
#pragma unroll
        for (int r = 0; r < 4; ++r) inv[r] = 1.0f / rsum[si][r];
        unsigned short* St = Ps[w][0];
#pragma unroll
        for (int dj = 0; dj < 4; ++dj)
#pragma unroll
            for (int r = 0; r < 4; ++r)
                St[(quad * 4 + r) * 72 + dj * 16 + lk] = f2b(oacc[si][dj][r] * inv[r]);
#pragma unroll
        for (int i = 0; i < 2; ++i) {
            const int row = lane >> 2, chk = (lane & 3) + 4 * i;
            uint4 d = *(const uint4*)(St + row * 72 + chk * 8);
            *(uint4*)(y + (rowbase + rq[si] + row) * 1024 + h * 64 + chk * 8) = d;
        }
    }
}

extern "C" void kernel_launch(void* const* d_in, const int* in_sizes, int n_in,
                              void* d_out, int out_size, void* d_ws, size_t ws_size,
                              hipStream_t stream) {
    const float* x   = (const float*)d_in[0];
    const float* wA  = (const float*)d_in[1];
    const float* wP  = (const float*)d_in[2];
    const float* wF  = (const float*)d_in[3];
    const float* wO  = (const float*)d_in[4];
    const float* g1  = (const float*)d_in[5];
    const float* b1  = (const float*)d_in[6];
    const float* g2  = (const float*)d_in[7];
    const float* b2v = (const float*)d_in[8];

    char* ws = (char*)d_ws;
    unsigned short* WaT  = (unsigned short*)(ws + OFF_WAT);
    unsigned short* WpT  = (unsigned short*)(ws + OFF_WPT);
    unsigned short* WfT  = (unsigned short*)(ws + OFF_WFT);
    unsigned short* WoT  = (unsigned short*)(ws + OFF_WOT);
    unsigned short* xn1  = (unsigned short*)(ws + OFF_R1);
    unsigned short* qkv  = (unsigned short*)(ws + OFF_R2);
    unsigned short* gbuf = (unsigned short*)(ws + OFF_R2);
    unsigned short* vt   = (unsigned short*)(ws + OFF_VT);
    unsigned short* y    = (unsigned short*)(ws + OFF_Y);
    float*          x2   = (float*)(ws + OFF_X2);
    unsigned short* h2   = xn1;
    float*          outf = (float*)d_out;

    // weight transposes + LN1 fused
    prep_kernel<<<16384, 256, 0, stream>>>(wA, wP, wF, wO, WaT, WpT, WfT, WoT,
                                           x, g1, b1, xn1);
    // qkv = xn1 @ w_attn, V-third written transposed into vt
    gemm_bt<3, 128><<<dim3(24, 32), 256, 0, stream>>>(xn1, WaT, qkv, nullptr, vt,
                                                      4096, 3072, 1024);
    attn_kernel<<<512, 256, 0, stream>>>(qkv, vt, y);
    // x2 = x + y @ w_proj (f32)
    gemm_bt<2, 64><<<dim3(16, 32), 256, 0, stream>>>(y, WpT, x2, x, nullptr,
                                                     4096, 1024, 1024);
    // LN2 + outf = x2 (residual base for the split-K atomic out GEMM)
    ln_kernel<<<4096, 256, 0, stream>>>(x2, g2, b2v, h2, outf);
    // g = gelu(h2 @ w_fc)
    gemm_bt<1, 128><<<dim3(32, 32), 256, 0, stream>>>(h2, WfT, gbuf, nullptr, nullptr,
                                                      4096, 4096, 1024);
    // out += g @ w_out  (split-K=4, atomic f32 accumulate)
    gemm_bt<4, 128><<<dim3(8, 32, 4), 256, 0, stream>>>(gbuf, WoT, outf, nullptr, nullptr,
                                                        4096, 1024, 4096);
}

// Round 11
// 341.333 us; speedup vs baseline: 1.0809x; 1.0809x over previous
//
#include <hip/hip_runtime.h>

typedef short s16x8 __attribute__((ext_vector_type(8)));
typedef float f32x4 __attribute__((ext_vector_type(4)));

#define MFMA16(a, b, c) __builtin_amdgcn_mfma_f32_16x16x32_bf16((a), (b), (c), 0, 0, 0)

// ---------- bf16 helpers (RNE) ----------
__device__ __forceinline__ float b2f(unsigned short u) {
    union { unsigned int i; float f; } c;
    c.i = ((unsigned int)u) << 16;
    return c.f;
}
__device__ __forceinline__ unsigned short f2b(float f) {
    union { float f; unsigned int i; } c;
    c.f = f;
    unsigned int i = c.i + 0x7FFFu + ((c.i >> 16) & 1u);
    return (unsigned short)(i >> 16);
}

// async global->LDS, 16B per lane; LDS dest = wave-uniform base + lane*16 [m97/m104]
__device__ __forceinline__ void gl_lds16(const unsigned short* g, unsigned short* l) {
    __builtin_amdgcn_global_load_lds(
        (const __attribute__((address_space(1))) void*)g,
        (__attribute__((address_space(3))) void*)l, 16, 0, 0);
}

// cheap exact-enough GELU: 0.5v(1+tanh(0.79788456(v+0.044715v^3))) via one exp
__device__ __forceinline__ float gelu_f(float v) {
    float u2 = 1.5957691216057308f * v * (1.0f + 0.044715f * v * v);  // 2u
    float t = __expf(fminf(u2, 80.0f));
    return v * t * __builtin_amdgcn_rcpf(t + 1.0f);
}

// ---------- problem constants ----------
// B=2, T=2048, D=1024, H=16, HD=64, M = B*T = 4096. f32 I/O, bf16 internals.
// Offsets (bytes):
//   WaT 0..6.29M, WpT ..8.39M, WfT ..16.78M   <- all dead by out-GEMM time: p0 reuses [0..16.78M)
//   WoT 16.78M..25.17M (live through out-GEMM)
//   R1 (xn1/h2) 25.17M..33.55M
//   R2 (qkv -> gbuf[4096][4096]) 33.55M..67.11M  ** gbuf tail covers VT region! **
//   VT 58.72M..67.11M (vt, dead after attention; overwritten by gbuf tail)
//   Y  67.11M..75.50M
//   X2 75.50M..92.27M
static constexpr size_t OFF_WAT = 0;
static constexpr size_t OFF_WPT = OFF_WAT + 6291456;
static constexpr size_t OFF_WFT = OFF_WPT + 2097152;
static constexpr size_t OFF_WOT = OFF_WFT + 8388608;
static constexpr size_t OFF_R1  = OFF_WOT + 8388608;
static constexpr size_t OFF_R2  = OFF_R1 + 8388608;
static constexpr size_t OFF_VT  = OFF_R2 + 25165824;
static constexpr size_t OFF_Y   = OFF_VT + 8388608;
static constexpr size_t OFF_X2  = OFF_Y + 8388608;

// ---------- fused: 4 weight transposes (f32->bf16) + LN1 ----------
__global__ __launch_bounds__(256) void prep_kernel(const float* __restrict__ wA,
                                                   const float* __restrict__ wP,
                                                   const float* __restrict__ wF,
                                                   const float* __restrict__ wO,
                                                   unsigned short* __restrict__ WaT,
                                                   unsigned short* __restrict__ WpT,
                                                   unsigned short* __restrict__ WfT,
                                                   unsigned short* __restrict__ WoT,
                                                   const float* __restrict__ x,
                                                   const float* __restrict__ g1,
                                                   const float* __restrict__ b1,
                                                   unsigned short* __restrict__ xn1) {
    __shared__ unsigned short tile[32][33];
    __shared__ float red[2][4];
    const int bb = blockIdx.x;
    if (bb >= 12288) {
        const int row = bb - 12288;
        const int t = threadIdx.x;
        float4 f = ((const float4*)(x + (size_t)row * 1024))[t];
        float v[4] = {f.x, f.y, f.z, f.w};
        float s = v[0] + v[1] + v[2] + v[3];
        float ss = v[0] * v[0] + v[1] * v[1] + v[2] * v[2] + v[3] * v[3];
#pragma unroll
        for (int o = 32; o >= 1; o >>= 1) {
            s += __shfl_down(s, o);
            ss += __shfl_down(ss, o);
        }
        const int wv = t >> 6, ln = t & 63;
        if (ln == 0) { red[0][wv] = s; red[1][wv] = ss; }
        __syncthreads();
        s = red[0][0] + red[0][1] + red[0][2] + red[0][3];
        ss = red[1][0] + red[1][1] + red[1][2] + red[1][3];
        const float mu = s * (1.0f / 1024.0f);
        const float rs = rsqrtf(ss * (1.0f / 1024.0f) - mu * mu + 1e-5f);
        float4 gg = ((const float4*)g1)[t];
        float4 bbv = ((const float4*)b1)[t];
        ushort4 o4;
        o4.x = f2b((v[0] - mu) * rs * gg.x + bbv.x);
        o4.y = f2b((v[1] - mu) * rs * gg.y + bbv.y);
        o4.z = f2b((v[2] - mu) * rs * gg.z + bbv.z);
        o4.w = f2b((v[3] - mu) * rs * gg.w + bbv.w);
        ((ushort4*)(xn1 + (size_t)row * 1024))[t] = o4;
        return;
    }
    const float* W;
    unsigned short* Wt;
    int K, N, rel;
    if (bb < 3072)      { W = wA; Wt = WaT; K = 1024; N = 3072; rel = bb; }
    else if (bb < 4096) { W = wP; Wt = WpT; K = 1024; N = 1024; rel = bb - 3072; }
    else if (bb < 8192) { W = wF; Wt = WfT; K = 1024; N = 4096; rel = bb - 4096; }
    else                { W = wO; Wt = WoT; K = 4096; N = 1024; rel = bb - 8192; }
    const int ntx = N >> 5;
    const int n0 = (rel % ntx) * 32, k0 = (rel / ntx) * 32;
    const int tx = threadIdx.x & 31, ty = threadIdx.x >> 5;  // 32 x 8
#pragma unroll
    for (int i = 0; i < 32; i += 8)
        tile[ty + i][tx] = f2b(W[(size_t)(k0 + ty + i) * N + (n0 + tx)]);
    __syncthreads();
#pragma unroll
    for (int i = 0; i < 32; i += 8)
        Wt[(size_t)(n0 + ty + i) * K + (k0 + tx)] = tile[tx][ty + i];
}

// ---------- layernorm: 1 block / row, D=1024, f32 in, bf16 out ----------
__global__ __launch_bounds__(256) void ln_kernel(const float* __restrict__ xin,
                                                 const float* __restrict__ gw,
                                                 const float* __restrict__ bw,
                                                 unsigned short* __restrict__ out) {
    const int row = blockIdx.x;
    const int t = threadIdx.x;
    float4 f = ((const float4*)(xin + (size_t)row * 1024))[t];
    float v[4] = {f.x, f.y, f.z, f.w};
    float s = v[0] + v[1] + v[2] + v[3];
    float ss = v[0] * v[0] + v[1] * v[1] + v[2] * v[2] + v[3] * v[3];
#pragma unroll
    for (int o = 32; o >= 1; o >>= 1) {
        s += __shfl_down(s, o);
        ss += __shfl_down(ss, o);
    }
    __shared__ float red[2][4];
    const int wv = t >> 6, ln = t & 63;
    if (ln == 0) { red[0][wv] = s; red[1][wv] = ss; }
    __syncthreads();
    s = red[0][0] + red[0][1] + red[0][2] + red[0][3];
    ss = red[1][0] + red[1][1] + red[1][2] + red[1][3];
    const float mu = s * (1.0f / 1024.0f);
    const float rs = rsqrtf(ss * (1.0f / 1024.0f) - mu * mu + 1e-5f);
    float4 gg = ((const float4*)gw)[t];
    float4 bb = ((const float4*)bw)[t];
    ushort4 o4;
    o4.x = f2b((v[0] - mu) * rs * gg.x + bb.x);
    o4.y = f2b((v[1] - mu) * rs * gg.y + bb.y);
    o4.z = f2b((v[2] - mu) * rs * gg.z + bb.z);
    o4.w = f2b((v[3] - mu) * rs * gg.w + bb.w);
    ((ushort4*)(out + (size_t)row * 1024))[t] = o4;
}

// ---------- combine: out = x2 + p0 + out(p1) ----------
__global__ __launch_bounds__(256) void combine_kernel(float* __restrict__ outf,
                                                      const float* __restrict__ x2,
                                                      const float* __restrict__ p0) {
    const size_t i = (size_t)blockIdx.x * 256 + threadIdx.x;
    float4 a = ((const float4*)x2)[i];
    float4 b = ((const float4*)p0)[i];
    float4 c = ((float4*)outf)[i];
    c.x += a.x + b.x; c.y += a.y + b.y; c.z += a.z + b.z; c.w += a.w + b.w;
    ((float4*)outf)[i] = c;
}

// ---------- GEMM: C[M][N] = A[M][K] @ Bt[N][K]^T ----------
// 128xBN tile, BK=64, global_load_lds staging, XOR-swizzled LDS (chunk ^= row&7).
// EPI: 0 = bf16 store; 1 = gelu -> bf16; 2 = f32 out = f32 resid + acc;
//      3 = qkv (V transposed to vt); 5 = split-K=2 plain f32 partial store
//      (z=0 -> residp-as-p0 buffer, z=1 -> outp)
template <int EPI, int BN>
__global__ __launch_bounds__(256) void gemm_bt(const unsigned short* __restrict__ A,
                                               const unsigned short* __restrict__ Bt,
                                               void* __restrict__ outp,
                                               const float* __restrict__ residp,
                                               unsigned short* __restrict__ vtp,
                                               int M, int N, int K) {
    constexpr int NWC = (BN == 128) ? 2 : 1;  // wave cols
    constexpr int AI  = (BN == 128) ? 4 : 2;  // 16-row groups per wave
    constexpr int PB  = BN / 32;              // B staging instrs per wave
    __shared__ unsigned short As[128 * 64];
    __shared__ unsigned short Bs[BN * 64];
    const int m0 = blockIdx.y * 128, n0 = blockIdx.x * BN;
    const int tid = threadIdx.x;
    const int w = tid >> 6, lane = tid & 63, quad = lane >> 4, lk = lane & 15;
    const int wr = w / NWC, wc = w % NWC;
    const int lrow = lane >> 3, lchunk = lane & 7;
    const int cg = lchunk ^ (lrow & 7);  // global 16B-chunk this lane fetches

    const unsigned short* aP = A + (size_t)(m0 + w * 32 + lrow) * K + cg * 8;
    const unsigned short* bP = Bt + (size_t)(n0 + w * (BN / 4) + lrow) * K + cg * 8;
    unsigned short* lA = As + (w * 32) * 64;
    unsigned short* lB = Bs + (w * (BN / 4)) * 64;

    f32x4 acc[AI][4];
#pragma unroll
    for (int i = 0; i < AI; ++i)
#pragma unroll
        for (int j = 0; j < 4; ++j) acc[i][j] = (f32x4){0.f, 0.f, 0.f, 0.f};

    // split-K (EPI 5): blockIdx.z selects a 32-iteration K-half
    const int kb0 = (EPI == 5) ? blockIdx.z * 32 : 0;
    const int kb1 = (EPI == 5) ? kb0 + 32 : (K >> 6);
    for (int kb = kb0; kb < kb1; ++kb) {
        const unsigned short* aPk = aP + kb * 64;
        const unsigned short* bPk = bP + kb * 64;
#pragma unroll
        for (int p = 0; p < 4; ++p)
            gl_lds16(aPk + (size_t)p * 8 * K, lA + p * 8 * 64);
#pragma unroll
        for (int p = 0; p < PB; ++p)
            gl_lds16(bPk + (size_t)p * 8 * K, lB + p * 8 * 64);
        __syncthreads();  // drains vmcnt -> LDS tiles visible
#pragma unroll
        for (int ks = 0; ks < 2; ++ks) {
            const int s = (ks * 4 + quad) ^ (lk & 7);
            s16x8 af[AI], bfv[4];
#pragma unroll
            for (int i = 0; i < AI; ++i)
                af[i] = *(const s16x8*)(As + (wr * (AI * 16) + i * 16 + lk) * 64 + s * 8);
#pragma unroll
            for (int j = 0; j < 4; ++j)
                bfv[j] = *(const s16x8*)(Bs + (wc * 64 + j * 16 + lk) * 64 + s * 8);
#pragma unroll
            for (int i = 0; i < AI; ++i)
#pragma unroll
                for (int j = 0; j < 4; ++j)
                    acc[i][j] = MFMA16(af[i], bfv[j], acc[i][j]);
        }
        __syncthreads();  // protect LDS before next overwrite
    }

    // epilogue: C/D layout col = lane&15, row = quad*4 + reg  [m89-verified]
    const int gr0 = m0 + wr * (AI * 16);
    const int gc0 = n0 + wc * 64;
    if constexpr (EPI == 2) {
#pragma unroll
        for (int i = 0; i < AI; ++i)
#pragma unroll
            for (int r = 0; r < 4; ++r) {
                const int gr = gr0 + i * 16 + quad * 4 + r;
                const size_t ro = (size_t)gr * N;
#pragma unroll
                for (int j = 0; j < 4; ++j) {
                    const int gc = gc0 + j * 16 + lk;
                    ((float*)outp)[ro + gc] = residp[ro + gc] + acc[i][j][r];
                }
            }
    } else if constexpr (EPI == 5) {
        // split-K: plain f32 partial store; z=0 -> p0 (residp), z=1 -> outp
        float* dst = (blockIdx.z == 0) ? (float*)residp : (float*)outp;
#pragma unroll
        for (int i = 0; i < AI; ++i)
#pragma unroll
            for (int r = 0; r < 4; ++r) {
                const int gr = gr0 + i * 16 + quad * 4 + r;
                const size_t ro = (size_t)gr * N;
#pragma unroll
                for (int j = 0; j < 4; ++j) {
                    const int gc = gc0 + j * 16 + lk;
                    dst[ro + gc] = acc[i][j][r];
                }
            }
    } else if (EPI == 3 && gc0 >= 2048) {
        // V block: store transposed into vt[(bh*64+d)*2048 + t]
        const int h = (gc0 - 2048) >> 6;
        const int bq = m0 >> 11;
        const size_t vb = (size_t)(bq * 16 + h) * 64;
        const int tg0 = (m0 & 2047) + wr * (AI * 16);
        unsigned short* Ept = As + w * 2048;  // [64 d][24] shorts (16B-aligned rows)
#pragma unroll
        for (int i = 0; i < AI; ++i) {
#pragma unroll
            for (int j = 0; j < 4; ++j)
#pragma unroll
                for (int r = 0; r < 4; ++r)
                    Ept[(j * 16 + lk) * 24 + quad * 4 + r] = f2b(acc[i][j][r]);
            const int d = lane;
#pragma unroll
            for (int half = 0; half < 2; ++half) {
                uint4 dd = *(const uint4*)(Ept + d * 24 + half * 8);
                *(uint4*)(vtp + (vb + d) * 2048 + tg0 + i * 16 + half * 8) = dd;
            }
        }
    } else {
        // bf16: stage through LDS, reload 16B/lane, full-line dwordx4 stores
        unsigned short* Ep = As + w * (16 * 72);  // per-wave [16][72] bf16
#pragma unroll
        for (int i = 0; i < AI; ++i) {
#pragma unroll
            for (int j = 0; j < 4; ++j)
#pragma unroll
                for (int r = 0; r < 4; ++r) {
                    float v = acc[i][j][r];
                    if constexpr (EPI == 1) v = gelu_f(v);
                    Ep[(quad * 4 + r) * 72 + j * 16 + lk] = f2b(v);
                }
#pragma unroll
            for (int c = 0; c < 2; ++c) {
                const int row = c * 8 + lrow;
                uint4 d = *(const uint4*)(Ep + row * 72 + lchunk * 8);
                const int gr = gr0 + i * 16 + row;
                *(uint4*)((unsigned short*)outp + (size_t)gr * N + gc0 + lchunk * 8) = d;
            }
        }
    }
}

// ---------- causal flash attention, GEMM-shaped (R6-verified) ----------
__global__ __launch_bounds__(256) void attn_kernel(const unsigned short* __restrict__ qkv,
                                                   const unsigned short* __restrict__ vt,
                                                   unsigned short* __restrict__ y) {
    __shared__ unsigned short Ks[64 * 64];            // [key][d], swizzled
    __shared__ unsigned short Vs[64 * 64];            // [d][key], swizzled
    __shared__ __align__(16) unsigned short Ps[4][2][576];  // per wave, per subtile [16][36]
    const int tid = threadIdx.x;
    const int w = tid >> 6, lane = tid & 63, quad = lane >> 4, lk = lane & 15;
    const int bb = blockIdx.x;
    const int bh = bb & 31;
    const int p = bb >> 5;               // 0..15
    const int b = bh >> 4, h = bh & 15;
    const size_t rowbase = (size_t)b * 2048;
    const size_t vbase = (size_t)bh * 64;
    const int nt = 32 - p;               // staged k-tiles
    const int rq[2] = {p * 64 + w * 16, (31 - p) * 64 + w * 16};

    const int lrow = lane >> 3, lchunk = lane & 7;

    // Q fragments for both subtiles (A-layout), pre-scaled by 1/8 (exact)
    s16x8 qf[2][2];
#pragma unroll
    for (int si = 0; si < 2; ++si)
#pragma unroll
        for (int ks = 0; ks < 2; ++ks) {
            s16x8 q = *(const s16x8*)(qkv + (rowbase + rq[si] + lk) * 3072 + h * 64 +
                                      ks * 32 + quad * 8);
#pragma unroll
            for (int e = 0; e < 8; ++e) {
                union { unsigned int i; float f; } cc;
                cc.i = ((unsigned int)(unsigned short)q[e]) << 16;
                cc.f *= 0.125f;
                q[e] = (short)(cc.i >> 16);
            }
            qf[si][ks] = q;
        }

    f32x4 oacc[2][4];
    float rsum[2][4];
#pragma unroll
    for (int si = 0; si < 2; ++si) {
#pragma unroll
        for (int dj = 0; dj < 4; ++dj) oacc[si][dj] = (f32x4){0.f, 0.f, 0.f, 0.f};
#pragma unroll
        for (int r = 0; r < 4; ++r) rsum[si][r] = 0.f;
    }

    const int srow = w * 16 + lrow;
    const int cgs = lchunk ^ (srow & 7);
    const unsigned short* kgp = qkv + (rowbase + srow) * 3072 + 1024 + h * 64 + cgs * 8;
    const unsigned short* vgp = vt + (vbase + srow) * 2048 + cgs * 8;
    unsigned short* kl = Ks + w * 1024;
    unsigned short* vl = Vs + w * 1024;

    for (int t = 0; t < nt; ++t) {
#pragma unroll
        for (int i = 0; i < 2; ++i) {
            gl_lds16(kgp + ((size_t)t * 64 + i * 8) * 3072, kl + i * 512);
            gl_lds16(vgp + t * 64 + (size_t)i * 8 * 2048, vl + i * 512);
        }
        __syncthreads();
#pragma unroll
        for (int half = 0; half < 2; ++half) {
            const int k0 = t * 64 + half * 32;
            s16x8 kf[2][2], vf[4];
#pragma unroll
            for (int nj = 0; nj < 2; ++nj)
#pragma unroll
                for (int ks = 0; ks < 2; ++ks) {
                    const int row = half * 32 + nj * 16 + lk;
                    const int s = (ks * 4 + quad) ^ (lk & 7);
                    kf[nj][ks] = *(const s16x8*)(Ks + row * 64 + s * 8);
                }
#pragma unroll
            for (int dj = 0; dj < 4; ++dj) {
                const int s = (half * 4 + quad) ^ (lk & 7);
                vf[dj] = *(const s16x8*)(Vs + (dj * 16 + lk) * 64 + s * 8);
            }
#pragma unroll
            for (int si = 0; si < 2; ++si) {
                const int r0 = rq[si];
                if (k0 > r0 + 15) continue;
                const bool domask = (k0 + 31 > r0);
                f32x4 s[2];
                s[0] = (f32x4){0.f, 0.f, 0.f, 0.f};
                s[1] = (f32x4){0.f, 0.f, 0.f, 0.f};
#pragma unroll
                for (int ks = 0; ks < 2; ++ks) {
                    s[0] = MFMA16(qf[si][ks], kf[0][ks], s[0]);
                    s[1] = MFMA16(qf[si][ks], kf[1][ks], s[1]);
                }
                unsigned short* Pw = Ps[w][si];
#pragma unroll
                for (int nj = 0; nj < 2; ++nj)
#pragma unroll
                    for (int r = 0; r < 4; ++r) {
                        float pv = __expf(s[nj][r]);
                        if (domask) {
                            const int key = k0 + nj * 16 + lk;
                            const int row = r0 + quad * 4 + r;
                            if (key > row) pv = 0.f;
                        }
                        union { float f; unsigned int i; } cc;
                        cc.f = pv;
                        cc.i &= 0xFFFF0000u;
                        rsum[si][r] += cc.f;
                        Pw[(quad * 4 + r) * 36 + nj * 16 + lk] = (unsigned short)(cc.i >> 16);
                    }
                const s16x8 af = *(const s16x8*)(Pw + lk * 36 + quad * 8);
#pragma unroll
                for (int dj = 0; dj < 4; ++dj)
                    oacc[si][dj] = MFMA16(af, vf[dj], oacc[si][dj]);
            }
        }
        __syncthreads();
    }

#pragma unroll
    for (int si = 0; si < 2; ++si) {
#pragma unroll
        for (int o = 1; o < 16; o <<= 1)
#pragma unroll
            for (int r = 0; r < 4; ++r) rsum[si][r] += __shfl_xor(rsum[si][r], o);
        float inv[4];
#pragma unroll
        for (int r = 0; r < 4; ++r) inv[r] = 1.0f / rsum[si][r];
        unsigned short* St = Ps[w][0];
#pragma unroll
        for (int dj = 0; dj < 4; ++dj)
#pragma unroll
            for (int r = 0; r < 4; ++r)
                St[(quad * 4 + r) * 72 + dj * 16 + lk] = f2b(oacc[si][dj][r] * inv[r]);
#pragma unroll
        for (int i = 0; i < 2; ++i) {
            const int row = lane >> 2, chk = (lane & 3) + 4 * i;
            uint4 d = *(const uint4*)(St + row * 72 + chk * 8);
            *(uint4*)(y + (rowbase + rq[si] + row) * 1024 + h * 64 + chk * 8) = d;
        }
    }
}

extern "C" void kernel_launch(void* const* d_in, const int* in_sizes, int n_in,
                              void* d_out, int out_size, void* d_ws, size_t ws_size,
                              hipStream_t stream) {
    const float* x   = (const float*)d_in[0];
    const float* wA  = (const float*)d_in[1];
    const float* wP  = (const float*)d_in[2];
    const float* wF  = (const float*)d_in[3];
    const float* wO  = (const float*)d_in[4];
    const float* g1  = (const float*)d_in[5];
    const float* b1  = (const float*)d_in[6];
    const float* g2  = (const float*)d_in[7];
    const float* b2v = (const float*)d_in[8];

    char* ws = (char*)d_ws;
    unsigned short* WaT  = (unsigned short*)(ws + OFF_WAT);
    unsigned short* WpT  = (unsigned short*)(ws + OFF_WPT);
    unsigned short* WfT  = (unsigned short*)(ws + OFF_WFT);
    unsigned short* WoT  = (unsigned short*)(ws + OFF_WOT);
    unsigned short* xn1  = (unsigned short*)(ws + OFF_R1);
    unsigned short* qkv  = (unsigned short*)(ws + OFF_R2);
    unsigned short* gbuf = (unsigned short*)(ws + OFF_R2);
    unsigned short* vt   = (unsigned short*)(ws + OFF_VT);
    unsigned short* y    = (unsigned short*)(ws + OFF_Y);
    float*          x2   = (float*)(ws + OFF_X2);
    // p0: reuse WaT+WpT+WfT (0..16.78 MB) — dead by out-GEMM time; does NOT
    // overlap gbuf (33.5M..67.1M), WoT (16.78M..25.17M), or x2.
    float*          p0   = (float*)(ws + OFF_WAT);
    unsigned short* h2   = xn1;
    float*          outf = (float*)d_out;

    // weight transposes + LN1 fused
    prep_kernel<<<16384, 256, 0, stream>>>(wA, wP, wF, wO, WaT, WpT, WfT, WoT,
                                           x, g1, b1, xn1);
    // qkv = xn1 @ w_attn, V-third written transposed into vt
    gemm_bt<3, 128><<<dim3(24, 32), 256, 0, stream>>>(xn1, WaT, qkv, nullptr, vt,
                                                      4096, 3072, 1024);
    attn_kernel<<<512, 256, 0, stream>>>(qkv, vt, y);
    // x2 = x + y @ w_proj (f32)
    gemm_bt<2, 64><<<dim3(16, 32), 256, 0, stream>>>(y, WpT, x2, x, nullptr,
                                                     4096, 1024, 1024);
    ln_kernel<<<4096, 256, 0, stream>>>(x2, g2, b2v, h2);
    // g = gelu(h2 @ w_fc)
    gemm_bt<1, 128><<<dim3(32, 32), 256, 0, stream>>>(h2, WfT, gbuf, nullptr, nullptr,
                                                      4096, 4096, 1024);
    // out partials: z=0 -> p0, z=1 -> outf (split-K=2, 32 iters each)
    gemm_bt<5, 64><<<dim3(16, 32, 2), 256, 0, stream>>>(gbuf, WoT, outf, p0, nullptr,
                                                        4096, 1024, 4096);
    // out = x2 + p0 + out
    combine_kernel<<<4096, 256, 0, stream>>>(outf, x2, p0);
}

// Round 12
// 326.946 us; speedup vs baseline: 1.1285x; 1.0440x over previous
//
#include <hip/hip_runtime.h>

typedef short s16x8 __attribute__((ext_vector_type(8)));
typedef float f32x4 __attribute__((ext_vector_type(4)));

#define MFMA16(a, b, c) __builtin_amdgcn_mfma_f32_16x16x32_bf16((a), (b), (c), 0, 0, 0)

// ---------- bf16 helpers (RNE) ----------
__device__ __forceinline__ float b2f(unsigned short u) {
    union { unsigned int i; float f; } c;
    c.i = ((unsigned int)u) << 16;
    return c.f;
}
__device__ __forceinline__ unsigned short f2b(float f) {
    union { float f; unsigned int i; } c;
    c.f = f;
    unsigned int i = c.i + 0x7FFFu + ((c.i >> 16) & 1u);
    return (unsigned short)(i >> 16);
}

// async global->LDS, 16B per lane; LDS dest = wave-uniform base + lane*16 [m97/m104]
__device__ __forceinline__ void gl_lds16(const unsigned short* g, unsigned short* l) {
    __builtin_amdgcn_global_load_lds(
        (const __attribute__((address_space(1))) void*)g,
        (__attribute__((address_space(3))) void*)l, 16, 0, 0);
}

// cheap exact-enough GELU: 0.5v(1+tanh(0.79788456(v+0.044715v^3))) via one exp
__device__ __forceinline__ float gelu_f(float v) {
    float u2 = 1.5957691216057308f * v * (1.0f + 0.044715f * v * v);  // 2u
    float t = __expf(fminf(u2, 80.0f));
    return v * t * __builtin_amdgcn_rcpf(t + 1.0f);
}

// ---------- problem constants ----------
// B=2, T=2048, D=1024, H=16, HD=64, M = B*T = 4096. f32 I/O, bf16 internals.
static constexpr size_t OFF_WAT = 0;
static constexpr size_t OFF_WPT = OFF_WAT + 6291456;
static constexpr size_t OFF_WFT = OFF_WPT + 2097152;
static constexpr size_t OFF_WOT = OFF_WFT + 8388608;
static constexpr size_t OFF_R1  = OFF_WOT + 8388608;
static constexpr size_t OFF_R2  = OFF_R1 + 8388608;          // qkv / gbuf (gbuf covers VT!)
static constexpr size_t OFF_VT  = OFF_R2 + 25165824;
static constexpr size_t OFF_Y   = OFF_VT + 8388608;
static constexpr size_t OFF_X2  = OFF_Y + 8388608;

// ---------- fused: 4 weight transposes (f32->bf16) + LN1 ----------
__global__ __launch_bounds__(256) void prep_kernel(const float* __restrict__ wA,
                                                   const float* __restrict__ wP,
                                                   const float* __restrict__ wF,
                                                   const float* __restrict__ wO,
                                                   unsigned short* __restrict__ WaT,
                                                   unsigned short* __restrict__ WpT,
                                                   unsigned short* __restrict__ WfT,
                                                   unsigned short* __restrict__ WoT,
                                                   const float* __restrict__ x,
                                                   const float* __restrict__ g1,
                                                   const float* __restrict__ b1,
                                                   unsigned short* __restrict__ xn1) {
    __shared__ unsigned short tile[32][33];
    __shared__ float red[2][4];
    const int bb = blockIdx.x;
    if (bb >= 12288) {
        const int row = bb - 12288;
        const int t = threadIdx.x;
        float4 f = ((const float4*)(x + (size_t)row * 1024))[t];
        float v[4] = {f.x, f.y, f.z, f.w};
        float s = v[0] + v[1] + v[2] + v[3];
        float ss = v[0] * v[0] + v[1] * v[1] + v[2] * v[2] + v[3] * v[3];
#pragma unroll
        for (int o = 32; o >= 1; o >>= 1) {
            s += __shfl_down(s, o);
            ss += __shfl_down(ss, o);
        }
        const int wv = t >> 6, ln = t & 63;
        if (ln == 0) { red[0][wv] = s; red[1][wv] = ss; }
        __syncthreads();
        s = red[0][0] + red[0][1] + red[0][2] + red[0][3];
        ss = red[1][0] + red[1][1] + red[1][2] + red[1][3];
        const float mu = s * (1.0f / 1024.0f);
        const float rs = rsqrtf(ss * (1.0f / 1024.0f) - mu * mu + 1e-5f);
        float4 gg = ((const float4*)g1)[t];
        float4 bbv = ((const float4*)b1)[t];
        ushort4 o4;
        o4.x = f2b((v[0] - mu) * rs * gg.x + bbv.x);
        o4.y = f2b((v[1] - mu) * rs * gg.y + bbv.y);
        o4.z = f2b((v[2] - mu) * rs * gg.z + bbv.z);
        o4.w = f2b((v[3] - mu) * rs * gg.w + bbv.w);
        ((ushort4*)(xn1 + (size_t)row * 1024))[t] = o4;
        return;
    }
    const float* W;
    unsigned short* Wt;
    int K, N, rel;
    if (bb < 3072)      { W = wA; Wt = WaT; K = 1024; N = 3072; rel = bb; }
    else if (bb < 4096) { W = wP; Wt = WpT; K = 1024; N = 1024; rel = bb - 3072; }
    else if (bb < 8192) { W = wF; Wt = WfT; K = 1024; N = 4096; rel = bb - 4096; }
    else                { W = wO; Wt = WoT; K = 4096; N = 1024; rel = bb - 8192; }
    const int ntx = N >> 5;
    const int n0 = (rel % ntx) * 32, k0 = (rel / ntx) * 32;
    const int tx = threadIdx.x & 31, ty = threadIdx.x >> 5;  // 32 x 8
#pragma unroll
    for (int i = 0; i < 32; i += 8)
        tile[ty + i][tx] = f2b(W[(size_t)(k0 + ty + i) * N + (n0 + tx)]);
    __syncthreads();
#pragma unroll
    for (int i = 0; i < 32; i += 8)
        Wt[(size_t)(n0 + ty + i) * K + (k0 + tx)] = tile[tx][ty + i];
}

// ---------- layernorm: 1 block / row, D=1024, f32 in, bf16 out ----------
__global__ __launch_bounds__(256) void ln_kernel(const float* __restrict__ xin,
                                                 const float* __restrict__ gw,
                                                 const float* __restrict__ bw,
                                                 unsigned short* __restrict__ out) {
    const int row = blockIdx.x;
    const int t = threadIdx.x;
    float4 f = ((const float4*)(xin + (size_t)row * 1024))[t];
    float v[4] = {f.x, f.y, f.z, f.w};
    float s = v[0] + v[1] + v[2] + v[3];
    float ss = v[0] * v[0] + v[1] * v[1] + v[2] * v[2] + v[3] * v[3];
#pragma unroll
    for (int o = 32; o >= 1; o >>= 1) {
        s += __shfl_down(s, o);
        ss += __shfl_down(ss, o);
    }
    __shared__ float red[2][4];
    const int wv = t >> 6, ln = t & 63;
    if (ln == 0) { red[0][wv] = s; red[1][wv] = ss; }
    __syncthreads();
    s = red[0][0] + red[0][1] + red[0][2] + red[0][3];
    ss = red[1][0] + red[1][1] + red[1][2] + red[1][3];
    const float mu = s * (1.0f / 1024.0f);
    const float rs = rsqrtf(ss * (1.0f / 1024.0f) - mu * mu + 1e-5f);
    float4 gg = ((const float4*)gw)[t];
    float4 bb = ((const float4*)bw)[t];
    ushort4 o4;
    o4.x = f2b((v[0] - mu) * rs * gg.x + bb.x);
    o4.y = f2b((v[1] - mu) * rs * gg.y + bb.y);
    o4.z = f2b((v[2] - mu) * rs * gg.z + bb.z);
    o4.w = f2b((v[3] - mu) * rs * gg.w + bb.w);
    ((ushort4*)(out + (size_t)row * 1024))[t] = o4;
}

// ---------- GEMM: C[M][N] = A[M][K] @ Bt[N][K]^T ----------
// 128xBN tile, BK=64, global_load_lds staging, XOR-swizzled LDS (chunk ^= row&7).
// 1-D grid with XCD-aware mapping (M always 4096 -> 32 m-blocks = 8 XCDs x 4):
//   xcd = lin&7 owns m-strips [xcd*4, xcd*4+4) for ALL n -> the large A matrix
//   is fetched once per owning XCD's L2 instead of 8x.
// EPI: 0 = bf16 store; 1 = gelu -> bf16; 2 = f32 out = f32 resid + acc;
//      3 = qkv (V cols transposed to vt)
template <int EPI, int BN>
__global__ __launch_bounds__(256) void gemm_bt(const unsigned short* __restrict__ A,
                                               const unsigned short* __restrict__ Bt,
                                               void* __restrict__ outp,
                                               const float* __restrict__ residp,
                                               unsigned short* __restrict__ vtp,
                                               int M, int N, int K) {
    constexpr int NWC = (BN == 128) ? 2 : 1;  // wave cols
    constexpr int AI  = (BN == 128) ? 4 : 2;  // 16-row groups per wave
    constexpr int PB  = BN / 32;              // B staging instrs per wave
    __shared__ unsigned short As[128 * 64];
    __shared__ unsigned short Bs[BN * 64];
    const int lin = blockIdx.x;
    const int xcd = lin & 7, loc = lin >> 3;
    const int m0 = (xcd * 4 + (loc & 3)) * 128;
    const int n0 = (loc >> 2) * BN;
    const int tid = threadIdx.x;
    const int w = tid >> 6, lane = tid & 63, quad = lane >> 4, lk = lane & 15;
    const int wr = w / NWC, wc = w % NWC;
    const int lrow = lane >> 3, lchunk = lane & 7;
    const int cg = lchunk ^ (lrow & 7);  // global 16B-chunk this lane fetches

    const unsigned short* aP = A + (size_t)(m0 + w * 32 + lrow) * K + cg * 8;
    const unsigned short* bP = Bt + (size_t)(n0 + w * (BN / 4) + lrow) * K + cg * 8;
    unsigned short* lA = As + (w * 32) * 64;
    unsigned short* lB = Bs + (w * (BN / 4)) * 64;

    f32x4 acc[AI][4];
#pragma unroll
    for (int i = 0; i < AI; ++i)
#pragma unroll
        for (int j = 0; j < 4; ++j) acc[i][j] = (f32x4){0.f, 0.f, 0.f, 0.f};

    const int KT = K >> 6;
    for (int kb = 0; kb < KT; ++kb) {
        const unsigned short* aPk = aP + kb * 64;
        const unsigned short* bPk = bP + kb * 64;
#pragma unroll
        for (int p = 0; p < 4; ++p)
            gl_lds16(aPk + (size_t)p * 8 * K, lA + p * 8 * 64);
#pragma unroll
        for (int p = 0; p < PB; ++p)
            gl_lds16(bPk + (size_t)p * 8 * K, lB + p * 8 * 64);
        __syncthreads();  // drains vmcnt -> LDS tiles visible
#pragma unroll
        for (int ks = 0; ks < 2; ++ks) {
            const int s = (ks * 4 + quad) ^ (lk & 7);
            s16x8 af[AI], bfv[4];
#pragma unroll
            for (int i = 0; i < AI; ++i)
                af[i] = *(const s16x8*)(As + (wr * (AI * 16) + i * 16 + lk) * 64 + s * 8);
#pragma unroll
            for (int j = 0; j < 4; ++j)
                bfv[j] = *(const s16x8*)(Bs + (wc * 64 + j * 16 + lk) * 64 + s * 8);
#pragma unroll
            for (int i = 0; i < AI; ++i)
#pragma unroll
                for (int j = 0; j < 4; ++j)
                    acc[i][j] = MFMA16(af[i], bfv[j], acc[i][j]);
        }
        __syncthreads();  // protect LDS before next overwrite
    }

    // epilogue: C/D layout col = lane&15, row = quad*4 + reg  [m89-verified]
    const int gr0 = m0 + wr * (AI * 16);
    const int gc0 = n0 + wc * 64;
    if constexpr (EPI == 2) {
#pragma unroll
        for (int i = 0; i < AI; ++i)
#pragma unroll
            for (int r = 0; r < 4; ++r) {
                const int gr = gr0 + i * 16 + quad * 4 + r;
                const size_t ro = (size_t)gr * N;
#pragma unroll
                for (int j = 0; j < 4; ++j) {
                    const int gc = gc0 + j * 16 + lk;
                    ((float*)outp)[ro + gc] = residp[ro + gc] + acc[i][j][r];
                }
            }
    } else if (EPI == 3 && gc0 >= 2048) {
        // V block: store transposed into vt[(bh*64+d)*2048 + t]
        const int h = (gc0 - 2048) >> 6;
        const int bq = m0 >> 11;
        const size_t vb = (size_t)(bq * 16 + h) * 64;
        const int tg0 = (m0 & 2047) + wr * (AI * 16);
        unsigned short* Ept = As + w * 2048;  // [64 d][24] shorts (16B-aligned rows)
#pragma unroll
        for (int i = 0; i < AI; ++i) {
#pragma unroll
            for (int j = 0; j < 4; ++j)
#pragma unroll
                for (int r = 0; r < 4; ++r)
                    Ept[(j * 16 + lk) * 24 + quad * 4 + r] = f2b(acc[i][j][r]);
            const int d = lane;
#pragma unroll
            for (int half = 0; half < 2; ++half) {
                uint4 dd = *(const uint4*)(Ept + d * 24 + half * 8);
                *(uint4*)(vtp + (vb + d) * 2048 + tg0 + i * 16 + half * 8) = dd;
            }
        }
    } else {
        // bf16: stage through LDS, reload 16B/lane, full-line dwordx4 stores
        unsigned short* Ep = As + w * (16 * 72);  // per-wave [16][72] bf16
#pragma unroll
        for (int i = 0; i < AI; ++i) {
#pragma unroll
            for (int j = 0; j < 4; ++j)
#pragma unroll
                for (int r = 0; r < 4; ++r) {
                    float v = acc[i][j][r];
                    if constexpr (EPI == 1) v = gelu_f(v);
                    Ep[(quad * 4 + r) * 72 + j * 16 + lk] = f2b(v);
                }
#pragma unroll
            for (int c = 0; c < 2; ++c) {
                const int row = c * 8 + lrow;
                uint4 d = *(const uint4*)(Ep + row * 72 + lchunk * 8);
                const int gr = gr0 + i * 16 + row;
                *(uint4*)((unsigned short*)outp + (size_t)gr * N + gc0 + lchunk * 8) = d;
            }
        }
    }
}

// ---------- causal flash attention, GEMM-shaped (R6-verified) ----------
__global__ __launch_bounds__(256) void attn_kernel(const unsigned short* __restrict__ qkv,
                                                   const unsigned short* __restrict__ vt,
                                                   unsigned short* __restrict__ y) {
    __shared__ unsigned short Ks[64 * 64];            // [key][d], swizzled
    __shared__ unsigned short Vs[64 * 64];            // [d][key], swizzled
    __shared__ __align__(16) unsigned short Ps[4][2][576];  // per wave, per subtile [16][36]
    const int tid = threadIdx.x;
    const int w = tid >> 6, lane = tid & 63, quad = lane >> 4, lk = lane & 15;
    const int bb = blockIdx.x;
    const int bh = bb & 31;
    const int p = bb >> 5;               // 0..15
    const int b = bh >> 4, h = bh & 15;
    const size_t rowbase = (size_t)b * 2048;
    const size_t vbase = (size_t)bh * 64;
    const int nt = 32 - p;               // staged k-tiles
    const int rq[2] = {p * 64 + w * 16, (31 - p) * 64 + w * 16};

    const int lrow = lane >> 3, lchunk = lane & 7;

    // Q fragments for both subtiles (A-layout), pre-scaled by 1/8 (exact)
    s16x8 qf[2][2];
#pragma unroll
    for (int si = 0; si < 2; ++si)
#pragma unroll
        for (int ks = 0; ks < 2; ++ks) {
            s16x8 q = *(const s16x8*)(qkv + (rowbase + rq[si] + lk) * 3072 + h * 64 +
                                      ks * 32 + quad * 8);
#pragma unroll
            for (int e = 0; e < 8; ++e) {
                union { unsigned int i; float f; } cc;
                cc.i = ((unsigned int)(unsigned short)q[e]) << 16;
                cc.f *= 0.125f;
                q[e] = (short)(cc.i >> 16);
            }
            qf[si][ks] = q;
        }

    f32x4 oacc[2][4];
    float rsum[2][4];
#pragma unroll
    for (int si = 0; si < 2; ++si) {
#pragma unroll
        for (int dj = 0; dj < 4; ++dj) oacc[si][dj] = (f32x4){0.f, 0.f, 0.f, 0.f};
#pragma unroll
        for (int r = 0; r < 4; ++r) rsum[si][r] = 0.f;
    }

    const int srow = w * 16 + lrow;
    const int cgs = lchunk ^ (srow & 7);
    const unsigned short* kgp = qkv + (rowbase + srow) * 3072 + 1024 + h * 64 + cgs * 8;
    const unsigned short* vgp = vt + (vbase + srow) * 2048 + cgs * 8;
    unsigned short* kl = Ks + w * 1024;
    unsigned short* vl = Vs + w * 1024;

    for (int t = 0; t < nt; ++t) {
#pragma unroll
        for (int i = 0; i < 2; ++i) {
            gl_lds16(kgp + ((size_t)t * 64 + i * 8) * 3072, kl + i * 512);
            gl_lds16(vgp + t * 64 + (size_t)i * 8 * 2048, vl + i * 512);
        }
        __syncthreads();
#pragma unroll
        for (int half = 0; half < 2; ++half) {
            const int k0 = t * 64 + half * 32;
            s16x8 kf[2][2], vf[4];
#pragma unroll
            for (int nj = 0; nj < 2; ++nj)
#pragma unroll
                for (int ks = 0; ks < 2; ++ks) {
                    const int row = half * 32 + nj * 16 + lk;
                    const int s = (ks * 4 + quad) ^ (lk & 7);
                    kf[nj][ks] = *(const s16x8*)(Ks + row * 64 + s * 8);
                }
#pragma unroll
            for (int dj = 0; dj < 4; ++dj) {
                const int s = (half * 4 + quad) ^ (lk & 7);
                vf[dj] = *(const s16x8*)(Vs + (dj * 16 + lk) * 64 + s * 8);
            }
#pragma unroll
            for (int si = 0; si < 2; ++si) {
                const int r0 = rq[si];
                if (k0 > r0 + 15) continue;
                const bool domask = (k0 + 31 > r0);
                f32x4 s[2];
                s[0] = (f32x4){0.f, 0.f, 0.f, 0.f};
                s[1] = (f32x4){0.f, 0.f, 0.f, 0.f};
#pragma unroll
                for (int ks = 0; ks < 2; ++ks) {
                    s[0] = MFMA16(qf[si][ks], kf[0][ks], s[0]);
                    s[1] = MFMA16(qf[si][ks], kf[1][ks], s[1]);
                }
                unsigned short* Pw = Ps[w][si];
#pragma unroll
                for (int nj = 0; nj < 2; ++nj)
#pragma unroll
                    for (int r = 0; r < 4; ++r) {
                        float pv = __expf(s[nj][r]);
                        if (domask) {
                            const int key = k0 + nj * 16 + lk;
                            const int row = r0 + quad * 4 + r;
                            if (key > row) pv = 0.f;
                        }
                        union { float f; unsigned int i; } cc;
                        cc.f = pv;
                        cc.i &= 0xFFFF0000u;
                        rsum[si][r] += cc.f;
                        Pw[(quad * 4 + r) * 36 + nj * 16 + lk] = (unsigned short)(cc.i >> 16);
                    }
                const s16x8 af = *(const s16x8*)(Pw + lk * 36 + quad * 8);
#pragma unroll
                for (int dj = 0; dj < 4; ++dj)
                    oacc[si][dj] = MFMA16(af, vf[dj], oacc[si][dj]);
            }
        }
        __syncthreads();
    }

#pragma unroll
    for (int si = 0; si < 2; ++si) {
#pragma unroll
        for (int o = 1; o < 16; o <<= 1)
#pragma unroll
            for (int r = 0; r < 4; ++r) rsum[si][r] += __shfl_xor(rsum[si][r], o);
        float inv[4];
#pragma unroll
        for (int r = 0; r < 4; ++r) inv[r] = 1.0f / rsum[si][r];
        unsigned short* St = Ps[w][0];
#pragma unroll
        for (int dj = 0; dj < 4; ++dj)
#pragma unroll
            for (int r = 0; r < 4; ++r)
                St[(quad * 4 + r) * 72 + dj * 16 + lk] = f2b(oacc[si][dj][r] * inv[r]);
#pragma unroll
        for (int i = 0; i < 2; ++i) {
            const int row = lane >> 2, chk = (lane & 3) + 4 * i;
            uint4 d = *(const uint4*)(St + row * 72 + chk * 8);
            *(uint4*)(y + (rowbase + rq[si] + row) * 1024 + h * 64 + chk * 8) = d;
        }
    }
}

extern "C" void kernel_launch(void* const* d_in, const int* in_sizes, int n_in,
                              void* d_out, int out_size, void* d_ws, size_t ws_size,
                              hipStream_t stream) {
    const float* x   = (const float*)d_in[0];
    const float* wA  = (const float*)d_in[1];
    const float* wP  = (const float*)d_in[2];
    const float* wF  = (const float*)d_in[3];
    const float* wO  = (const float*)d_in[4];
    const float* g1  = (const float*)d_in[5];
    const float* b1  = (const float*)d_in[6];
    const float* g2  = (const float*)d_in[7];
    const float* b2v = (const float*)d_in[8];

    char* ws = (char*)d_ws;
    unsigned short* WaT  = (unsigned short*)(ws + OFF_WAT);
    unsigned short* WpT  = (unsigned short*)(ws + OFF_WPT);
    unsigned short* WfT  = (unsigned short*)(ws + OFF_WFT);
    unsigned short* WoT  = (unsigned short*)(ws + OFF_WOT);
    unsigned short* xn1  = (unsigned short*)(ws + OFF_R1);
    unsigned short* qkv  = (unsigned short*)(ws + OFF_R2);
    unsigned short* gbuf = (unsigned short*)(ws + OFF_R2);
    unsigned short* vt   = (unsigned short*)(ws + OFF_VT);
    unsigned short* y    = (unsigned short*)(ws + OFF_Y);
    float*          x2   = (float*)(ws + OFF_X2);
    unsigned short* h2   = xn1;
    float*          outf = (float*)d_out;

    // weight transposes + LN1 fused
    prep_kernel<<<16384, 256, 0, stream>>>(wA, wP, wF, wO, WaT, WpT, WfT, WoT,
                                           x, g1, b1, xn1);
    // qkv = xn1 @ w_attn, V-third written transposed into vt  (24 n-blocks x 32 m)
    gemm_bt<3, 128><<<768, 256, 0, stream>>>(xn1, WaT, qkv, nullptr, vt,
                                             4096, 3072, 1024);
    attn_kernel<<<512, 256, 0, stream>>>(qkv, vt, y);
    // x2 = x + y @ w_proj (f32)  (16 n-blocks x 32 m)
    gemm_bt<2, 64><<<512, 256, 0, stream>>>(y, WpT, x2, x, nullptr,
                                            4096, 1024, 1024);
    ln_kernel<<<4096, 256, 0, stream>>>(x2, g2, b2v, h2);
    // g = gelu(h2 @ w_fc)  (32 n-blocks x 32 m)
    gemm_bt<1, 128><<<1024, 256, 0, stream>>>(h2, WfT, gbuf, nullptr, nullptr,
                                              4096, 4096, 1024);
    // out = x2 + g @ w_out (f32)  (16 n-blocks x 32 m)
    gemm_bt<2, 64><<<512, 256, 0, stream>>>(gbuf, WoT, outf, x2, nullptr,
                                            4096, 1024, 4096);
}